// Round 5
// baseline (199.174 us; speedup 1.0000x reference)
//
#include <hip/hip_runtime.h>
#include <hip/hip_bf16.h>
#include <math.h>

// Problem constants
#define B_  8
#define S_  128
#define HID_ 256
#define H_  4
#define DH_ 64
#define FF_ 1024
#define M_  (B_ * S_)   // 1024 rows

typedef _Float16 half_t;
typedef __attribute__((ext_vector_type(4))) _Float16 half4;
typedef __attribute__((ext_vector_type(8))) _Float16 half8;
typedef __attribute__((ext_vector_type(4))) float floatx4;

enum { EP_F32 = 0, EP_F16 = 1, EP_F16B = 2, EP_GELU = 3, EP_PROJ = 4 };

__device__ __forceinline__ floatx4 mfma16(half8 a, half8 b, floatx4 c) {
    return __builtin_amdgcn_mfma_f32_16x16x32_f16(a, b, c, 0, 0, 0);
}

// ---------------- reductions ----------------
// 16-lane (quad-group) reductions: shfl_xor < 16 stays within the group
__device__ __forceinline__ float qred_sum(float v) {
#pragma unroll
    for (int o = 1; o < 16; o <<= 1) v += __shfl_xor(v, o, 64);
    return v;
}
__device__ __forceinline__ float qred_max(float v) {
#pragma unroll
    for (int o = 1; o < 16; o <<= 1) v = fmaxf(v, __shfl_xor(v, o, 64));
    return v;
}
// softmax over 128 logits: 8 per lane across a 16-lane group
__device__ __forceinline__ void sm8(float (&v)[8]) {
    float m = v[0];
#pragma unroll
    for (int j = 1; j < 8; ++j) m = fmaxf(m, v[j]);
    m = qred_max(m);
    float s = 0.f;
#pragma unroll
    for (int j = 0; j < 8; ++j) { v[j] = expf(v[j] - m); s += v[j]; }
    s = qred_sum(s);
    float r = 1.f / s;
#pragma unroll
    for (int j = 0; j < 8; ++j) v[j] *= r;
}

// ---------------- fp16 MFMA GEMM core (64x64 tile) ----------------
template<int EPI>
__device__ __forceinline__ void mgemm(
    const half_t* __restrict__ A, int ldA,
    const half_t* __restrict__ Bt, int ldB,
    int kLen, int m0, int n0,
    const float* __restrict__ bias,
    float* __restrict__ Cf, half_t* __restrict__ Ch, int ldC,
    const float* __restrict__ pw1, const float* __restrict__ pw2,
    float* __restrict__ po1, float* __restrict__ po2, int hsel)
{
    __shared__ half8 Asf[2][4][64];
    __shared__ half8 Bsf[2][4][64];

    const int tid = threadIdx.x;
    const int w = tid >> 6, l = tid & 63;
    const int sr = tid >> 2;
    const int sq = tid & 3;
    const int sdst = (sr & 15) | (sq << 4);
    const int smt = sr >> 4;
    const half_t* Ap = A + (size_t)(m0 + sr) * ldA + sq * 8;
    const half_t* Bp = Bt + (size_t)(n0 + sr) * ldB + sq * 8;

    half8 ra, rb;
    auto fetch = [&](int t) {
        ra = *(const half8*)(Ap + t * 32);
        rb = *(const half8*)(Bp + t * 32);
    };
    auto commit = [&](int buf) {
        Asf[buf][smt][sdst] = ra;
        Bsf[buf][smt][sdst] = rb;
    };

    floatx4 zero = {0.f, 0.f, 0.f, 0.f};
    floatx4 acc[4] = {zero, zero, zero, zero};
    const int kt = kLen >> 5;

    fetch(0);
    commit(0);
    __syncthreads();
    for (int t = 0; t < kt; ++t) {
        const bool more = (t + 1 < kt);
        if (more) fetch(t + 1);
        const int buf = t & 1;
        half8 a = Asf[buf][w][l];
        acc[0] = mfma16(a, Bsf[buf][0][l], acc[0]);
        acc[1] = mfma16(a, Bsf[buf][1][l], acc[1]);
        acc[2] = mfma16(a, Bsf[buf][2][l], acc[2]);
        acc[3] = mfma16(a, Bsf[buf][3][l], acc[3]);
        __syncthreads();
        if (more) {
            commit((t + 1) & 1);
            __syncthreads();
        }
    }

    const int quad = l >> 4, lc = l & 15;
    const int rowb = m0 + w * 16 + quad * 4;
    float bvv[4] = {0.f, 0.f, 0.f, 0.f};
    if (EPI >= EP_F16B) {
#pragma unroll
        for (int nt = 0; nt < 4; ++nt) bvv[nt] = bias[n0 + nt * 16 + lc];
    }
    float pw1v[4], pw2v[4];
    if (EPI == EP_PROJ) {
#pragma unroll
        for (int nt = 0; nt < 4; ++nt) {
            pw1v[nt] = pw1[nt * 16 + lc];
            pw2v[nt] = pw2[nt * 16 + lc];
        }
    }
#pragma unroll
    for (int rr = 0; rr < 4; ++rr) {
        float ov[4];
#pragma unroll
        for (int nt = 0; nt < 4; ++nt) {
            float o = acc[nt][rr];
            if (EPI >= EP_F16B) o += bvv[nt];
            if (EPI == EP_GELU) o = 0.5f * o * (1.f + erff(o * 0.70710678118654752f));
            ov[nt] = o;
            const size_t ci = (size_t)(rowb + rr) * ldC + n0 + nt * 16 + lc;
            if (EPI == EP_F32) Cf[ci] = o;
            else Ch[ci] = (half_t)o;
        }
        if (EPI == EP_PROJ) {
            float po = ov[0] * pw1v[0] + ov[1] * pw1v[1] + ov[2] * pw1v[2] + ov[3] * pw1v[3];
            float pd = ov[0] * pw2v[0] + ov[1] * pw2v[1] + ov[2] * pw2v[2] + ov[3] * pw2v[3];
#pragma unroll
            for (int off = 1; off < 16; off <<= 1) {
                po += __shfl_xor(po, off, 64);
                pd += __shfl_xor(pd, off, 64);
            }
            if (lc == 0) {
                const int m = rowb + rr;
                const int idx = ((m >> 7) * H_ + hsel) * S_ + (m & 127);
                po1[idx] = po;
                po2[idx] = pd;
            }
        }
    }
}

// ---------------- prep: fp32 -> fp16 converts + transposes ----------------
__global__ __launch_bounds__(256) void prep_kernel(
    const float* __restrict__ x,
    const float* __restrict__ Wq, const float* __restrict__ Wk,
    const float* __restrict__ Wv, const float* __restrict__ Wd,
    const float* __restrict__ AWq, const float* __restrict__ AWk,
    const float* __restrict__ W1, const float* __restrict__ W2,
    half_t* __restrict__ x16, half_t* __restrict__ Wq16n, half_t* __restrict__ Wk16n,
    half_t* __restrict__ WqT, half_t* __restrict__ WkT, half_t* __restrict__ WvT,
    half_t* __restrict__ WdT, half_t* __restrict__ AWqT, half_t* __restrict__ AWkT,
    half_t* __restrict__ W1T, half_t* __restrict__ W2T)
{
    const int z = blockIdx.z, bx = blockIdx.x, by = blockIdx.y;
    const int tid = threadIdx.x;
    if (z < 3) {
        const float* src = (z == 0) ? x : (z == 1) ? Wq : Wk;
        half_t* dst = (z == 0) ? x16 : (z == 1) ? Wq16n : Wk16n;
        const int total = (z == 0) ? M_ * HID_ : HID_ * HID_;
        const int bid = by * 16 + bx;
        if (bid * 1024 < total) {
            const int base = bid * 1024 + tid * 4;
            float4 vv = *(const float4*)(src + base);
            dst[base + 0] = (half_t)vv.x;
            dst[base + 1] = (half_t)vv.y;
            dst[base + 2] = (half_t)vv.z;
            dst[base + 3] = (half_t)vv.w;
        }
        return;
    }
    const float* src; half_t* dst; int K, N, k0, n0;
    if (z <= 8) {
        const float* ins[6] = {Wq, Wk, Wv, Wd, AWq, AWk};
        half_t* outs[6] = {WqT, WkT, WvT, WdT, AWqT, AWkT};
        src = ins[z - 3]; dst = outs[z - 3];
        K = 256; N = 256; k0 = bx * 64; n0 = by * 64;
        if (bx >= 4 || by >= 4) return;
    } else if (z == 9) {
        src = W1; dst = W1T; K = 256; N = 1024;
        k0 = bx * 64; n0 = by * 64;
        if (bx >= 4) return;
    } else {
        src = W2; dst = W2T; K = 1024; N = 256;
        k0 = by * 64; n0 = bx * 64;
        if (bx >= 4) return;
    }
    __shared__ half_t tl[64][72];
    const int r = tid >> 2, c0 = (tid & 3) * 16;
#pragma unroll 4
    for (int i = 0; i < 16; ++i)
        tl[c0 + i][r] = (half_t)src[(size_t)(k0 + r) * N + n0 + c0 + i];
    __syncthreads();
#pragma unroll 4
    for (int i = 0; i < 16; ++i)
        dst[(size_t)(n0 + r) * K + k0 + c0 + i] = tl[r][c0 + i];
}

// ---------------- compose: WcT = AW^T @ W^T (fp16), bc = b@AW + Ab ----------
__global__ __launch_bounds__(256) void compose_mfma(
    const half_t* __restrict__ AWqT, const half_t* __restrict__ AWkT,
    const half_t* __restrict__ Wq16n, const half_t* __restrict__ Wk16n,
    const float* __restrict__ AWq, const float* __restrict__ AWk,
    const float* __restrict__ bq, const float* __restrict__ bk,
    const float* __restrict__ Abq, const float* __restrict__ Abk,
    half_t* __restrict__ WcqT, half_t* __restrict__ WckT,
    float* __restrict__ bcq, float* __restrict__ bck)
{
    const int z = blockIdx.z;
    if (blockIdx.y < 4) {
        const half_t* A = z ? AWkT : AWqT;
        const half_t* Bt = z ? Wk16n : Wq16n;
        half_t* C = z ? WckT : WcqT;
        mgemm<EP_F16>(A, HID_, Bt, HID_, HID_, blockIdx.y * 64, blockIdx.x * 64,
                      nullptr, nullptr, C, HID_, nullptr, nullptr, nullptr, nullptr, 0);
    } else {
        __shared__ float red[4][64];
        const float* bsrc = z ? bk : bq;
        const float* AW   = z ? AWk : AWq;
        const float* Ab   = z ? Abk : Abq;
        float* bco        = z ? bck : bcq;
        int t = threadIdx.x, l = t & 63, kc = t >> 6;
        int n = blockIdx.x * 64 + l;
        float p = 0.f;
#pragma unroll 8
        for (int kk = 0; kk < 64; ++kk) {
            int k = kc * 64 + kk;
            p = fmaf(bsrc[k], AW[(size_t)k * HID_ + n], p);
        }
        red[kc][l] = p;
        __syncthreads();
        if (kc == 0)
            bco[n] = red[0][l] + red[1][l] + red[2][l] + red[3][l] + Ab[n];
    }
}

// ---------------- 5 projections of x in one launch ----------------
__global__ __launch_bounds__(256) void xgemm5(
    const half_t* __restrict__ x16,
    const half_t* __restrict__ WqT, const float* __restrict__ bq,
    const half_t* __restrict__ WkT, const float* __restrict__ bk,
    const half_t* __restrict__ WvT, const float* __restrict__ bv,
    const half_t* __restrict__ WcqT, const float* __restrict__ bcq,
    const half_t* __restrict__ WckT, const float* __restrict__ bck,
    const float* __restrict__ order_w, const float* __restrict__ dist_w,
    half_t* __restrict__ q16, half_t* __restrict__ k16, half_t* __restrict__ v16,
    half_t* __restrict__ aq16, half_t* __restrict__ ak16,
    float* __restrict__ qoA, float* __restrict__ qdA,
    float* __restrict__ koA, float* __restrict__ kdA)
{
    const int z = blockIdx.z;
    const int m0 = blockIdx.y * 64, n0 = blockIdx.x * 64;
    if (z == 0)
        mgemm<EP_PROJ>(x16, HID_, WqT, HID_, HID_, m0, n0, bq, nullptr, q16, HID_,
                       order_w, dist_w, qoA, qdA, blockIdx.x);
    else if (z == 1)
        mgemm<EP_PROJ>(x16, HID_, WkT, HID_, HID_, m0, n0, bk, nullptr, k16, HID_,
                       order_w + DH_, dist_w + DH_, koA, kdA, blockIdx.x);
    else if (z == 2)
        mgemm<EP_F16B>(x16, HID_, WvT, HID_, HID_, m0, n0, bv, nullptr, v16, HID_,
                       nullptr, nullptr, nullptr, nullptr, 0);
    else if (z == 3)
        mgemm<EP_F16B>(x16, HID_, WcqT, HID_, HID_, m0, n0, bcq, nullptr, aq16, HID_,
                       nullptr, nullptr, nullptr, nullptr, 0);
    else
        mgemm<EP_F16B>(x16, HID_, WckT, HID_, HID_, m0, n0, bck, nullptr, ak16, HID_,
                       nullptr, nullptr, nullptr, nullptr, 0);
}

// ---------------- fused attention: scores + 5 softmaxes + PV ----------------
// grid = 64 blocks (bh*2 + it), 256 threads; block handles 64 q-rows, all 128 j
__global__ __launch_bounds__(256) void attn_fused(
    const half_t* __restrict__ q16, const half_t* __restrict__ k16,
    const half_t* __restrict__ v16, const half_t* __restrict__ aq16,
    const half_t* __restrict__ ak16,
    const float* __restrict__ qoA, const float* __restrict__ qdA,
    const float* __restrict__ koA, const float* __restrict__ kdA,
    const float* __restrict__ mask,
    const float* __restrict__ order_b_p, const float* __restrict__ dist_b_p,
    const float* __restrict__ scalar_p,
    half_t* __restrict__ ctx16)
{
    __shared__ half8 Qf[2][4][64], AQf[2][4][64];   // 8 KB + 8 KB
    __shared__ half8 Kf[2][8][64], AKf[2][8][64];   // 16 KB + 16 KB
    __shared__ half_t Vs[128][68];                  // 17 KB (pad 68: 4-way on frag reads)
    __shared__ half_t Pm[64][136];                  // 17 KB (rows 272 B, 16B-aligned frags)

    const int tid = threadIdx.x;
    const int w = tid >> 6, l = tid & 63;
    const int quad = l >> 4, lc = l & 15;
    const int bid = blockIdx.x;
    const int bh = bid >> 1, it = bid & 1;
    const int b = bh >> 2, h = bh & 3;
    const size_t hoff = (size_t)b * S_ * HID_ + h * DH_;

    // ---- stage Q/AQ (64 rows), K/AK/V (128 rows) as MFMA fragments ----
#pragma unroll
    for (int u = 0; u < 2; ++u) {
        int idx = tid * 2 + u;
        int r = idx >> 3, c = idx & 7;
        const size_t g = hoff + (size_t)(it * 64 + r) * HID_ + c * 8;
        int kt = c >> 2, mt = r >> 4, sl = (r & 15) | ((c & 3) << 4);
        Qf[kt][mt][sl]  = *(const half8*)(q16 + g);
        AQf[kt][mt][sl] = *(const half8*)(aq16 + g);
    }
#pragma unroll
    for (int u = 0; u < 4; ++u) {
        int idx = tid * 4 + u;
        int j = idx >> 3, c = idx & 7;
        const size_t g = hoff + (size_t)j * HID_ + c * 8;
        int kt = c >> 2, jt = j >> 4, sl = (j & 15) | ((c & 3) << 4);
        Kf[kt][jt][sl]  = *(const half8*)(k16 + g);
        AKf[kt][jt][sl] = *(const half8*)(ak16 + g);
        half8 vv = *(const half8*)(v16 + g);
        half4 v0 = {vv[0], vv[1], vv[2], vv[3]};
        half4 v1 = {vv[4], vv[5], vv[6], vv[7]};
        *(half4*)&Vs[j][c * 8]     = v0;
        *(half4*)&Vs[j][c * 8 + 4] = v1;
    }
    __syncthreads();

    // ---- S = Q.K^T, AS = AQ.AK^T (per wave: 16 rows x 128 j) ----
    floatx4 zero = {0.f, 0.f, 0.f, 0.f};
    floatx4 accS[8], accA[8];
#pragma unroll
    for (int jt = 0; jt < 8; ++jt) { accS[jt] = zero; accA[jt] = zero; }
#pragma unroll
    for (int kt = 0; kt < 2; ++kt) {
        half8 a0 = Qf[kt][w][l];
        half8 a1 = AQf[kt][w][l];
#pragma unroll
        for (int jt = 0; jt < 8; ++jt) {
            accS[jt] = mfma16(a0, Kf[kt][jt][l], accS[jt]);
            accA[jt] = mfma16(a1, AKf[kt][jt][l], accA[jt]);
        }
    }

    // ---- 5-softmax chain, all in registers (quad = one row) ----
    const float ob = order_b_p[0], db = dist_b_p[0];
    const float scl = scalar_p[0];
    const float s2 = scl * scl;
    const float inv = 0.125f;
    float kov[8], kdv[8];
#pragma unroll
    for (int jt = 0; jt < 8; ++jt) {
        kov[jt] = koA[bh * S_ + jt * 16 + lc];
        kdv[jt] = kdA[bh * S_ + jt * 16 + lc];
    }
    const int il_base = w * 16 + quad * 4;
#pragma unroll
    for (int reg = 0; reg < 4; ++reg) {
        const int il = il_base + reg;   // 0..63 local row
        const int i  = it * 64 + il;    // global query index
        float qo = qoA[bh * S_ + i], qd = qdA[bh * S_ + i];
        const float* mrow = mask + ((size_t)(b * S_ + i)) * S_;
        float mk[8], lg[8], as_[8];
#pragma unroll
        for (int jt = 0; jt < 8; ++jt) {
            mk[jt] = mrow[jt * 16 + lc];
            lg[jt] = accS[jt][reg];
            as_[jt] = accA[jt][reg];
        }
        float p0[8];
#pragma unroll
        for (int jt = 0; jt < 8; ++jt) p0[jt] = lg[jt] * inv + mk[jt];
        sm8(p0);                                    // origin_probs
        float p1[8];
#pragma unroll
        for (int jt = 0; jt < 8; ++jt) {
            int j = jt * 16 + lc;
            float pr = 1.f / (1.f + expf(-(qo + kov[jt] + ob)));
            float sel = (j > i) ? pr : 1.f - pr;
            float erro = logf(sel + 1e-24f);
            float gd = logf(fabsf((float)(j - i)) + 1.f);
            float dd = gd - (qd + kdv[jt] + db);
            p1[jt] = (lg[jt] + erro - 0.5f * dd * dd * s2) * inv + mk[jt];
        }
        sm8(p1);                                    // rich_probs
#pragma unroll
        for (int jt = 0; jt < 8; ++jt) p0[jt] += 0.5f * p1[jt];
        sm8(p0);                                    // combined
#pragma unroll
        for (int jt = 0; jt < 8; ++jt) p1[jt] = as_[jt] * inv + mk[jt];
        sm8(p1);                                    // attack_probs
#pragma unroll
        for (int jt = 0; jt < 8; ++jt) p0[jt] += 0.5f * p1[jt];
        sm8(p0);                                    // final_probs
#pragma unroll
        for (int jt = 0; jt < 8; ++jt) Pm[il][jt * 16 + lc] = (half_t)p0[jt];
    }
    __syncthreads();

    // ---- PV: ctx = P @ V via MFMA (P from LDS as A-frags, V as B-frags) ----
    half8 pa_[4];
#pragma unroll
    for (int kt = 0; kt < 4; ++kt)
        pa_[kt] = *(const half8*)&Pm[w * 16 + lc][kt * 32 + quad * 8];
    floatx4 apv[4];
#pragma unroll
    for (int nt = 0; nt < 4; ++nt) apv[nt] = zero;
#pragma unroll
    for (int nt = 0; nt < 4; ++nt) {
#pragma unroll
        for (int kt = 0; kt < 4; ++kt) {
            half8 vf;
#pragma unroll
            for (int e = 0; e < 8; ++e)
                vf[e] = Vs[kt * 32 + quad * 8 + e][nt * 16 + lc];
            apv[nt] = mfma16(pa_[kt], vf, apv[nt]);
        }
    }
#pragma unroll
    for (int nt = 0; nt < 4; ++nt) {
#pragma unroll
        for (int reg = 0; reg < 4; ++reg) {
            int i = it * 64 + w * 16 + quad * 4 + reg;
            ctx16[hoff + (size_t)i * HID_ + nt * 16 + lc] = (half_t)apv[nt][reg];
        }
    }
}

// ---------------- fused GEMM (N=256 full) + bias + residual + LN ----------
// grid 16 blocks (64-row m-tiles), 256 thr; wave holds full rows -> in-reg LN
template<int WRITE16>
__global__ __launch_bounds__(256) void gemmln(
    const half_t* __restrict__ A, const half_t* __restrict__ Bt, int K,
    const float* __restrict__ bias, const float* __restrict__ res,
    const float* __restrict__ g, const float* __restrict__ be,
    float* __restrict__ out32, half_t* __restrict__ out16)
{
    __shared__ half8 Asf[2][4][64];     // 8 KB
    __shared__ half8 Bsf[2][16][64];    // 32 KB

    const int tid = threadIdx.x;
    const int w = tid >> 6, l = tid & 63;
    const int quad = l >> 4, lc = l & 15;
    const int m0 = blockIdx.x * 64;

    const int ar = tid >> 2, aq_ = tid & 3;
    const half_t* Ap = A + (size_t)(m0 + ar) * K + aq_ * 8;
    const half_t* Bp = Bt + (size_t)tid * K;   // thread t stages row n=t, 32-k slice

    half8 ra, rb[4];
    auto fetch = [&](int t) {
        ra = *(const half8*)(Ap + t * 32);
        const half_t* bp = Bp + t * 32;
#pragma unroll
        for (int u = 0; u < 4; ++u) rb[u] = *(const half8*)(bp + u * 8);
    };
    auto commit = [&](int buf) {
        Asf[buf][ar >> 4][(ar & 15) | (aq_ << 4)] = ra;
#pragma unroll
        for (int u = 0; u < 4; ++u)
            Bsf[buf][tid >> 4][(tid & 15) | (u << 4)] = rb[u];
    };

    floatx4 zero = {0.f, 0.f, 0.f, 0.f};
    floatx4 acc[16];
#pragma unroll
    for (int nt = 0; nt < 16; ++nt) acc[nt] = zero;
    const int kt = K >> 5;

    fetch(0);
    commit(0);
    __syncthreads();
    for (int t = 0; t < kt; ++t) {
        const bool more = (t + 1 < kt);
        if (more) fetch(t + 1);
        const int buf = t & 1;
        half8 a = Asf[buf][w][l];
#pragma unroll
        for (int nt = 0; nt < 16; ++nt)
            acc[nt] = mfma16(a, Bsf[buf][nt][l], acc[nt]);
        __syncthreads();
        if (more) {
            commit((t + 1) & 1);
            __syncthreads();
        }
    }

    float bv[16], gg[16], bb[16];
#pragma unroll
    for (int nt = 0; nt < 16; ++nt) {
        bv[nt] = bias[nt * 16 + lc];
        gg[nt] = g[nt * 16 + lc];
        bb[nt] = be[nt * 16 + lc];
    }
#pragma unroll
    for (int reg = 0; reg < 4; ++reg) {
        const int row = m0 + w * 16 + quad * 4 + reg;
        const float* rr = res + (size_t)row * HID_;
        float vals[16];
        float s = 0.f;
#pragma unroll
        for (int nt = 0; nt < 16; ++nt) {
            vals[nt] = acc[nt][reg] + bv[nt] + rr[nt * 16 + lc];
            s += vals[nt];
        }
        s = qred_sum(s);
        float mean = s * (1.f / HID_);
        float vs = 0.f;
#pragma unroll
        for (int nt = 0; nt < 16; ++nt) {
            float d = vals[nt] - mean;
            vals[nt] = d;
            vs += d * d;
        }
        vs = qred_sum(vs);
        float rstd = rsqrtf(vs * (1.f / HID_) + 1e-12f);
#pragma unroll
        for (int nt = 0; nt < 16; ++nt) {
            float o = vals[nt] * rstd * gg[nt] + bb[nt];
            const size_t ci = (size_t)row * HID_ + nt * 16 + lc;
            out32[ci] = o;
            if (WRITE16) out16[ci] = (half_t)o;
        }
    }
}

// ---------------- ff1: h@W1+b1, GELU ----------------
__global__ __launch_bounds__(256) void ff1_mfma(
    const half_t* __restrict__ h16, const half_t* __restrict__ W1T,
    const float* __restrict__ b1, half_t* __restrict__ f116)
{
    mgemm<EP_GELU>(h16, HID_, W1T, HID_, HID_, blockIdx.y * 64, blockIdx.x * 64,
                   b1, nullptr, f116, FF_, nullptr, nullptr, nullptr, nullptr, 0);
}

// ---------------- launch ----------------
extern "C" void kernel_launch(void* const* d_in, const int* in_sizes, int n_in,
                              void* d_out, int out_size, void* d_ws, size_t ws_size,
                              hipStream_t stream) {
    const float* x        = (const float*)d_in[0];
    const float* mask     = (const float*)d_in[1];
    const float* Wq       = (const float*)d_in[2];
    const float* bq       = (const float*)d_in[3];
    const float* Wk       = (const float*)d_in[4];
    const float* bk       = (const float*)d_in[5];
    const float* Wv       = (const float*)d_in[6];
    const float* bv       = (const float*)d_in[7];
    const float* order_w  = (const float*)d_in[8];
    const float* order_b  = (const float*)d_in[9];
    const float* dist_w   = (const float*)d_in[10];
    const float* dist_b   = (const float*)d_in[11];
    const float* scalar   = (const float*)d_in[12];
    const float* AWq      = (const float*)d_in[13];
    const float* Abq      = (const float*)d_in[14];
    const float* AWk      = (const float*)d_in[15];
    const float* Abk      = (const float*)d_in[16];
    const float* Wd       = (const float*)d_in[17];
    const float* bd       = (const float*)d_in[18];
    const float* g1       = (const float*)d_in[19];
    const float* beta1    = (const float*)d_in[20];
    const float* W1       = (const float*)d_in[21];
    const float* b1       = (const float*)d_in[22];
    const float* W2       = (const float*)d_in[23];
    const float* b2       = (const float*)d_in[24];
    const float* g2       = (const float*)d_in[25];
    const float* beta2    = (const float*)d_in[26];

    float* ws = (float*)d_ws;
    size_t off = 0;
    auto afl = [&](size_t n) { float* p = ws + off; off += n; return p; };
    auto ahf = [&](size_t nh) { half_t* p = (half_t*)(ws + off); off += nh / 2; return p; };

    half_t* x16   = ahf(M_ * HID_);
    half_t* Wq16n = ahf(HID_ * HID_);
    half_t* Wk16n = ahf(HID_ * HID_);
    half_t* WqT   = ahf(HID_ * HID_);
    half_t* WkT   = ahf(HID_ * HID_);
    half_t* WvT   = ahf(HID_ * HID_);
    half_t* WdT   = ahf(HID_ * HID_);
    half_t* AWqT  = ahf(HID_ * HID_);
    half_t* AWkT  = ahf(HID_ * HID_);
    half_t* W1T   = ahf(HID_ * FF_);
    half_t* W2T   = ahf(HID_ * FF_);
    half_t* WcqT  = ahf(HID_ * HID_);
    half_t* WckT  = ahf(HID_ * HID_);
    half_t* q16   = ahf(M_ * HID_);
    half_t* k16   = ahf(M_ * HID_);
    half_t* v16   = ahf(M_ * HID_);
    half_t* aq16  = ahf(M_ * HID_);
    half_t* ak16  = ahf(M_ * HID_);
    half_t* ctx16 = ahf(M_ * HID_);
    half_t* h16   = ahf(M_ * HID_);
    half_t* f116  = ahf(M_ * FF_);
    float* hb32 = afl(M_ * HID_);
    float* bcq  = afl(256);
    float* bck  = afl(256);
    float* qoA  = afl(B_ * H_ * S_);
    float* qdA  = afl(B_ * H_ * S_);
    float* koA  = afl(B_ * H_ * S_);
    float* kdA  = afl(B_ * H_ * S_);

    prep_kernel<<<dim3(16, 16, 11), 256, 0, stream>>>(
        x, Wq, Wk, Wv, Wd, AWq, AWk, W1, W2,
        x16, Wq16n, Wk16n, WqT, WkT, WvT, WdT, AWqT, AWkT, W1T, W2T);
    compose_mfma<<<dim3(4, 5, 2), 256, 0, stream>>>(
        AWqT, AWkT, Wq16n, Wk16n, AWq, AWk, bq, bk, Abq, Abk, WcqT, WckT, bcq, bck);
    xgemm5<<<dim3(4, 16, 5), 256, 0, stream>>>(
        x16, WqT, bq, WkT, bk, WvT, bv, WcqT, bcq, WckT, bck, order_w, dist_w,
        q16, k16, v16, aq16, ak16, qoA, qdA, koA, kdA);
    attn_fused<<<64, 256, 0, stream>>>(
        q16, k16, v16, aq16, ak16, qoA, qdA, koA, kdA,
        mask, order_b, dist_b, scalar, ctx16);
    gemmln<1><<<16, 256, 0, stream>>>(ctx16, WdT, HID_, bd, x, g1, beta1, hb32, h16);
    ff1_mfma<<<dim3(16, 16), 256, 0, stream>>>(h16, W1T, b1, f116);
    gemmln<0><<<16, 256, 0, stream>>>(f116, W2T, FF_, b2, hb32, g2, beta2,
                                      (float*)d_out, nullptr);
}

// Round 6
// 195.740 us; speedup vs baseline: 1.0175x; 1.0175x over previous
//
#include <hip/hip_runtime.h>
#include <hip/hip_bf16.h>
#include <math.h>

// Problem constants
#define B_  8
#define S_  128
#define HID_ 256
#define H_  4
#define DH_ 64
#define FF_ 1024
#define M_  (B_ * S_)   // 1024 rows

typedef _Float16 half_t;
typedef __attribute__((ext_vector_type(8))) _Float16 half8;
typedef __attribute__((ext_vector_type(4))) float floatx4;

enum { EP_F32 = 0, EP_F16 = 1, EP_F16B = 2, EP_GELU = 3, EP_PROJ = 4 };

__device__ __forceinline__ floatx4 mfma16(half8 a, half8 b, floatx4 c) {
    return __builtin_amdgcn_mfma_f32_16x16x32_f16(a, b, c, 0, 0, 0);
}

// ---------------- reductions ----------------
__device__ __forceinline__ float qred_sum(float v) {
#pragma unroll
    for (int o = 1; o < 16; o <<= 1) v += __shfl_xor(v, o, 64);
    return v;
}
__device__ __forceinline__ float qred_max(float v) {
#pragma unroll
    for (int o = 1; o < 16; o <<= 1) v = fmaxf(v, __shfl_xor(v, o, 64));
    return v;
}
// softmax over 128 logits: 8 per lane across a 16-lane group
__device__ __forceinline__ void sm8(float (&v)[8]) {
    float m = v[0];
#pragma unroll
    for (int j = 1; j < 8; ++j) m = fmaxf(m, v[j]);
    m = qred_max(m);
    float s = 0.f;
#pragma unroll
    for (int j = 0; j < 8; ++j) { v[j] = expf(v[j] - m); s += v[j]; }
    s = qred_sum(s);
    float r = 1.f / s;
#pragma unroll
    for (int j = 0; j < 8; ++j) v[j] *= r;
}

// ---------------- fp16 MFMA GEMM core (64x64 tile) ----------------
template<int EPI>
__device__ __forceinline__ void mgemm(
    const half_t* __restrict__ A, int ldA,
    const half_t* __restrict__ Bt, int ldB,
    int kLen, int m0, int n0,
    const float* __restrict__ bias,
    float* __restrict__ Cf, half_t* __restrict__ Ch, int ldC,
    const float* __restrict__ pw1, const float* __restrict__ pw2,
    float* __restrict__ po1, float* __restrict__ po2, int hsel)
{
    __shared__ half8 Asf[2][4][64];
    __shared__ half8 Bsf[2][4][64];

    const int tid = threadIdx.x;
    const int w = tid >> 6, l = tid & 63;
    const int sr = tid >> 2;
    const int sq = tid & 3;
    const int sdst = (sr & 15) | (sq << 4);
    const int smt = sr >> 4;
    const half_t* Ap = A + (size_t)(m0 + sr) * ldA + sq * 8;
    const half_t* Bp = Bt + (size_t)(n0 + sr) * ldB + sq * 8;

    half8 ra, rb;
    auto fetch = [&](int t) {
        ra = *(const half8*)(Ap + t * 32);
        rb = *(const half8*)(Bp + t * 32);
    };
    auto commit = [&](int buf) {
        Asf[buf][smt][sdst] = ra;
        Bsf[buf][smt][sdst] = rb;
    };

    floatx4 zero = {0.f, 0.f, 0.f, 0.f};
    floatx4 acc[4] = {zero, zero, zero, zero};
    const int kt = kLen >> 5;

    fetch(0);
    commit(0);
    __syncthreads();
    for (int t = 0; t < kt; ++t) {
        const bool more = (t + 1 < kt);
        if (more) fetch(t + 1);
        const int buf = t & 1;
        half8 a = Asf[buf][w][l];
        acc[0] = mfma16(a, Bsf[buf][0][l], acc[0]);
        acc[1] = mfma16(a, Bsf[buf][1][l], acc[1]);
        acc[2] = mfma16(a, Bsf[buf][2][l], acc[2]);
        acc[3] = mfma16(a, Bsf[buf][3][l], acc[3]);
        __syncthreads();
        if (more) {
            commit((t + 1) & 1);
            __syncthreads();
        }
    }

    const int quad = l >> 4, lc = l & 15;
    const int rowb = m0 + w * 16 + quad * 4;
    float bvv[4] = {0.f, 0.f, 0.f, 0.f};
    if (EPI >= EP_F16B) {
#pragma unroll
        for (int nt = 0; nt < 4; ++nt) bvv[nt] = bias[n0 + nt * 16 + lc];
    }
    float pw1v[4], pw2v[4];
    if (EPI == EP_PROJ) {
#pragma unroll
        for (int nt = 0; nt < 4; ++nt) {
            pw1v[nt] = pw1[nt * 16 + lc];
            pw2v[nt] = pw2[nt * 16 + lc];
        }
    }
#pragma unroll
    for (int rr = 0; rr < 4; ++rr) {
        float ov[4];
#pragma unroll
        for (int nt = 0; nt < 4; ++nt) {
            float o = acc[nt][rr];
            if (EPI >= EP_F16B) o += bvv[nt];
            if (EPI == EP_GELU) o = 0.5f * o * (1.f + erff(o * 0.70710678118654752f));
            ov[nt] = o;
            const size_t ci = (size_t)(rowb + rr) * ldC + n0 + nt * 16 + lc;
            if (EPI == EP_F32) Cf[ci] = o;
            else Ch[ci] = (half_t)o;
        }
        if (EPI == EP_PROJ) {
            float po = ov[0] * pw1v[0] + ov[1] * pw1v[1] + ov[2] * pw1v[2] + ov[3] * pw1v[3];
            float pd = ov[0] * pw2v[0] + ov[1] * pw2v[1] + ov[2] * pw2v[2] + ov[3] * pw2v[3];
#pragma unroll
            for (int off = 1; off < 16; off <<= 1) {
                po += __shfl_xor(po, off, 64);
                pd += __shfl_xor(pd, off, 64);
            }
            if (lc == 0) {
                const int m = rowb + rr;
                const int idx = ((m >> 7) * H_ + hsel) * S_ + (m & 127);
                po1[idx] = po;
                po2[idx] = pd;
            }
        }
    }
}

// ---------------- prep: fp32 -> fp16 converts + transposes ----------------
__global__ __launch_bounds__(256) void prep_kernel(
    const float* __restrict__ x,
    const float* __restrict__ Wq, const float* __restrict__ Wk,
    const float* __restrict__ Wv, const float* __restrict__ Wd,
    const float* __restrict__ AWq, const float* __restrict__ AWk,
    const float* __restrict__ W1, const float* __restrict__ W2,
    half_t* __restrict__ x16, half_t* __restrict__ Wq16n, half_t* __restrict__ Wk16n,
    half_t* __restrict__ WqT, half_t* __restrict__ WkT, half_t* __restrict__ WvT,
    half_t* __restrict__ WdT, half_t* __restrict__ AWqT, half_t* __restrict__ AWkT,
    half_t* __restrict__ W1T, half_t* __restrict__ W2T)
{
    const int z = blockIdx.z, bx = blockIdx.x, by = blockIdx.y;
    const int tid = threadIdx.x;
    if (z < 3) {
        const float* src = (z == 0) ? x : (z == 1) ? Wq : Wk;
        half_t* dst = (z == 0) ? x16 : (z == 1) ? Wq16n : Wk16n;
        const int total = (z == 0) ? M_ * HID_ : HID_ * HID_;
        const int bid = by * 16 + bx;
        if (bid * 1024 < total) {
            const int base = bid * 1024 + tid * 4;
            float4 vv = *(const float4*)(src + base);
            dst[base + 0] = (half_t)vv.x;
            dst[base + 1] = (half_t)vv.y;
            dst[base + 2] = (half_t)vv.z;
            dst[base + 3] = (half_t)vv.w;
        }
        return;
    }
    const float* src; half_t* dst; int K, N, k0, n0;
    if (z <= 8) {
        const float* ins[6] = {Wq, Wk, Wv, Wd, AWq, AWk};
        half_t* outs[6] = {WqT, WkT, WvT, WdT, AWqT, AWkT};
        src = ins[z - 3]; dst = outs[z - 3];
        K = 256; N = 256; k0 = bx * 64; n0 = by * 64;
        if (bx >= 4 || by >= 4) return;
    } else if (z == 9) {
        src = W1; dst = W1T; K = 256; N = 1024;
        k0 = bx * 64; n0 = by * 64;
        if (bx >= 4) return;
    } else {
        src = W2; dst = W2T; K = 1024; N = 256;
        k0 = by * 64; n0 = bx * 64;
        if (bx >= 4) return;
    }
    __shared__ half_t tl[64][72];
    const int r = tid >> 2, c0 = (tid & 3) * 16;
#pragma unroll 4
    for (int i = 0; i < 16; ++i)
        tl[c0 + i][r] = (half_t)src[(size_t)(k0 + r) * N + n0 + c0 + i];
    __syncthreads();
#pragma unroll 4
    for (int i = 0; i < 16; ++i)
        dst[(size_t)(n0 + r) * K + k0 + c0 + i] = tl[r][c0 + i];
}

// ---------------- compose: WcT = AW^T @ W^T (fp16), bc = b@AW + Ab ----------
__global__ __launch_bounds__(256) void compose_mfma(
    const half_t* __restrict__ AWqT, const half_t* __restrict__ AWkT,
    const half_t* __restrict__ Wq16n, const half_t* __restrict__ Wk16n,
    const float* __restrict__ AWq, const float* __restrict__ AWk,
    const float* __restrict__ bq, const float* __restrict__ bk,
    const float* __restrict__ Abq, const float* __restrict__ Abk,
    half_t* __restrict__ WcqT, half_t* __restrict__ WckT,
    float* __restrict__ bcq, float* __restrict__ bck)
{
    const int z = blockIdx.z;
    if (blockIdx.y < 4) {
        const half_t* A = z ? AWkT : AWqT;
        const half_t* Bt = z ? Wk16n : Wq16n;
        half_t* C = z ? WckT : WcqT;
        mgemm<EP_F16>(A, HID_, Bt, HID_, HID_, blockIdx.y * 64, blockIdx.x * 64,
                      nullptr, nullptr, C, HID_, nullptr, nullptr, nullptr, nullptr, 0);
    } else {
        __shared__ float red[4][64];
        const float* bsrc = z ? bk : bq;
        const float* AW   = z ? AWk : AWq;
        const float* Ab   = z ? Abk : Abq;
        float* bco        = z ? bck : bcq;
        int t = threadIdx.x, l = t & 63, kc = t >> 6;
        int n = blockIdx.x * 64 + l;
        float p = 0.f;
#pragma unroll 8
        for (int kk = 0; kk < 64; ++kk) {
            int k = kc * 64 + kk;
            p = fmaf(bsrc[k], AW[(size_t)k * HID_ + n], p);
        }
        red[kc][l] = p;
        __syncthreads();
        if (kc == 0)
            bco[n] = red[0][l] + red[1][l] + red[2][l] + red[3][l] + Ab[n];
    }
}

// ---------------- 5 projections of x in one launch ----------------
__global__ __launch_bounds__(256) void xgemm5(
    const half_t* __restrict__ x16,
    const half_t* __restrict__ WqT, const float* __restrict__ bq,
    const half_t* __restrict__ WkT, const float* __restrict__ bk,
    const half_t* __restrict__ WvT, const float* __restrict__ bv,
    const half_t* __restrict__ WcqT, const float* __restrict__ bcq,
    const half_t* __restrict__ WckT, const float* __restrict__ bck,
    const float* __restrict__ order_w, const float* __restrict__ dist_w,
    half_t* __restrict__ q16, half_t* __restrict__ k16, half_t* __restrict__ v16,
    half_t* __restrict__ aq16, half_t* __restrict__ ak16,
    float* __restrict__ qoA, float* __restrict__ qdA,
    float* __restrict__ koA, float* __restrict__ kdA)
{
    const int z = blockIdx.z;
    const int m0 = blockIdx.y * 64, n0 = blockIdx.x * 64;
    if (z == 0)
        mgemm<EP_PROJ>(x16, HID_, WqT, HID_, HID_, m0, n0, bq, nullptr, q16, HID_,
                       order_w, dist_w, qoA, qdA, blockIdx.x);
    else if (z == 1)
        mgemm<EP_PROJ>(x16, HID_, WkT, HID_, HID_, m0, n0, bk, nullptr, k16, HID_,
                       order_w + DH_, dist_w + DH_, koA, kdA, blockIdx.x);
    else if (z == 2)
        mgemm<EP_F16B>(x16, HID_, WvT, HID_, HID_, m0, n0, bv, nullptr, v16, HID_,
                       nullptr, nullptr, nullptr, nullptr, 0);
    else if (z == 3)
        mgemm<EP_F16B>(x16, HID_, WcqT, HID_, HID_, m0, n0, bcq, nullptr, aq16, HID_,
                       nullptr, nullptr, nullptr, nullptr, 0);
    else
        mgemm<EP_F16B>(x16, HID_, WckT, HID_, HID_, m0, n0, bck, nullptr, ak16, HID_,
                       nullptr, nullptr, nullptr, nullptr, 0);
}

// ---------------- fused attention: scores + 5 softmaxes + PV ----------------
// grid = 64 blocks (bh*2 + it), 256 threads; block handles 64 q-rows, all 128 j
__global__ __launch_bounds__(256) void attn_fused(
    const half_t* __restrict__ q16, const half_t* __restrict__ k16,
    const half_t* __restrict__ v16, const half_t* __restrict__ aq16,
    const half_t* __restrict__ ak16,
    const float* __restrict__ qoA, const float* __restrict__ qdA,
    const float* __restrict__ koA, const float* __restrict__ kdA,
    const float* __restrict__ mask,
    const float* __restrict__ order_b_p, const float* __restrict__ dist_b_p,
    const float* __restrict__ scalar_p,
    half_t* __restrict__ ctx16)
{
    __shared__ half8 Qf[2][4][64], AQf[2][4][64];   // 8 KB + 8 KB
    __shared__ half8 Kf[2][8][64], AKf[2][8][64];   // 16 KB + 16 KB
    __shared__ half_t Vt[64][136];                  // 17 KB, V transposed [d][j]
    __shared__ half_t Pm[64][136];                  // 17 KB

    const int tid = threadIdx.x;
    const int w = tid >> 6, l = tid & 63;
    const int quad = l >> 4, lc = l & 15;
    const int bid = blockIdx.x;
    const int bh = bid >> 1, it = bid & 1;
    const int b = bh >> 2, h = bh & 3;
    const size_t hoff = (size_t)b * S_ * HID_ + h * DH_;

    // ---- stage Q/AQ (64 rows), K/AK (128 rows) as MFMA fragments ----
#pragma unroll
    for (int u = 0; u < 2; ++u) {
        int idx = tid * 2 + u;
        int r = idx >> 3, c = idx & 7;
        const size_t g = hoff + (size_t)(it * 64 + r) * HID_ + c * 8;
        int kt = c >> 2, mt = r >> 4, sl = (r & 15) | ((c & 3) << 4);
        Qf[kt][mt][sl]  = *(const half8*)(q16 + g);
        AQf[kt][mt][sl] = *(const half8*)(aq16 + g);
    }
#pragma unroll
    for (int u = 0; u < 4; ++u) {
        int idx = tid * 4 + u;
        int j = idx >> 3, c = idx & 7;
        const size_t g = hoff + (size_t)j * HID_ + c * 8;
        int kt = c >> 2, jt = j >> 4, sl = (j & 15) | ((c & 3) << 4);
        Kf[kt][jt][sl]  = *(const half8*)(k16 + g);
        AKf[kt][jt][sl] = *(const half8*)(ak16 + g);
    }
    // ---- stage V transposed: Vt[d][j] = v[j][d] ----
    {
        const int j = tid & 127;
        const int c0 = (tid >> 7) * 4;
#pragma unroll
        for (int cc = 0; cc < 4; ++cc) {
            const int c = c0 + cc;
            half8 vv = *(const half8*)(v16 + hoff + (size_t)j * HID_ + c * 8);
#pragma unroll
            for (int e = 0; e < 8; ++e) Vt[c * 8 + e][j] = vv[e];
        }
    }
    __syncthreads();

    // ---- S = Q.K^T, AS = AQ.AK^T (per wave: 16 rows x 128 j) ----
    floatx4 zero = {0.f, 0.f, 0.f, 0.f};
    floatx4 accS[8], accA[8];
#pragma unroll
    for (int jt = 0; jt < 8; ++jt) { accS[jt] = zero; accA[jt] = zero; }
#pragma unroll
    for (int kt = 0; kt < 2; ++kt) {
        half8 a0 = Qf[kt][w][l];
        half8 a1 = AQf[kt][w][l];
#pragma unroll
        for (int jt = 0; jt < 8; ++jt) {
            accS[jt] = mfma16(a0, Kf[kt][jt][l], accS[jt]);
            accA[jt] = mfma16(a1, AKf[kt][jt][l], accA[jt]);
        }
    }

    // ---- 5-softmax chain in registers (16-lane group = one row) ----
    const float ob = order_b_p[0], db = dist_b_p[0];
    const float scl = scalar_p[0];
    const float s2 = scl * scl;
    const float inv = 0.125f;
    float kov[8], kdv[8];
#pragma unroll
    for (int jt = 0; jt < 8; ++jt) {
        kov[jt] = koA[bh * S_ + jt * 16 + lc];
        kdv[jt] = kdA[bh * S_ + jt * 16 + lc];
    }
    const int il_base = w * 16 + quad * 4;
#pragma unroll
    for (int reg = 0; reg < 4; ++reg) {
        const int il = il_base + reg;
        const int i  = it * 64 + il;
        float qo = qoA[bh * S_ + i], qd = qdA[bh * S_ + i];
        const float* mrow = mask + ((size_t)(b * S_ + i)) * S_;
        float mk[8], lg[8], as_[8];
#pragma unroll
        for (int jt = 0; jt < 8; ++jt) {
            mk[jt] = mrow[jt * 16 + lc];
            lg[jt] = accS[jt][reg];
            as_[jt] = accA[jt][reg];
        }
        float p0[8];
#pragma unroll
        for (int jt = 0; jt < 8; ++jt) p0[jt] = lg[jt] * inv + mk[jt];
        sm8(p0);                                    // origin_probs
        float p1[8];
#pragma unroll
        for (int jt = 0; jt < 8; ++jt) {
            int j = jt * 16 + lc;
            float pr = 1.f / (1.f + expf(-(qo + kov[jt] + ob)));
            float sel = (j > i) ? pr : 1.f - pr;
            float erro = logf(sel + 1e-24f);
            float gd = logf(fabsf((float)(j - i)) + 1.f);
            float dd = gd - (qd + kdv[jt] + db);
            p1[jt] = (lg[jt] + erro - 0.5f * dd * dd * s2) * inv + mk[jt];
        }
        sm8(p1);                                    // rich_probs
#pragma unroll
        for (int jt = 0; jt < 8; ++jt) p0[jt] += 0.5f * p1[jt];
        sm8(p0);                                    // combined
#pragma unroll
        for (int jt = 0; jt < 8; ++jt) p1[jt] = as_[jt] * inv + mk[jt];
        sm8(p1);                                    // attack_probs
#pragma unroll
        for (int jt = 0; jt < 8; ++jt) p0[jt] += 0.5f * p1[jt];
        sm8(p0);                                    // final_probs
#pragma unroll
        for (int jt = 0; jt < 8; ++jt) Pm[il][jt * 16 + lc] = (half_t)p0[jt];
    }
    __syncthreads();

    // ---- PV: ctx = P @ V via MFMA (A-frags from Pm, B-frags from Vt; all b128)
    half8 pa_[4];
#pragma unroll
    for (int kt = 0; kt < 4; ++kt)
        pa_[kt] = *(const half8*)&Pm[w * 16 + lc][kt * 32 + quad * 8];
    floatx4 apv[4];
#pragma unroll
    for (int nt = 0; nt < 4; ++nt) apv[nt] = zero;
#pragma unroll
    for (int nt = 0; nt < 4; ++nt) {
#pragma unroll
        for (int kt = 0; kt < 4; ++kt) {
            half8 vf = *(const half8*)&Vt[nt * 16 + lc][kt * 32 + quad * 8];
            apv[nt] = mfma16(pa_[kt], vf, apv[nt]);
        }
    }
#pragma unroll
    for (int nt = 0; nt < 4; ++nt) {
#pragma unroll
        for (int reg = 0; reg < 4; ++reg) {
            int i = it * 64 + w * 16 + quad * 4 + reg;
            ctx16[hoff + (size_t)i * HID_ + nt * 16 + lc] = (half_t)apv[nt][reg];
        }
    }
}

// ---------------- fused GEMM (full N=256) + bias + residual + LN ----------
// grid 64 blocks (16-row tiles), 256 thr; wave w owns cols w*64..w*64+63;
// LN reduction crosses waves via one LDS exchange.
template<int WRITE16>
__global__ __launch_bounds__(256) void gemmln(
    const half_t* __restrict__ A, const half_t* __restrict__ Bt, int K,
    const float* __restrict__ bias, const float* __restrict__ res,
    const float* __restrict__ g, const float* __restrict__ be,
    float* __restrict__ out32, half_t* __restrict__ out16)
{
    __shared__ half8 Asf[2][64];        // 2 KB  (16 rows x 32 k)
    __shared__ half8 Bsf[2][16][64];    // 32 KB (256 n x 32 k)
    __shared__ float rsum[4][16], rsq[4][16];

    const int tid = threadIdx.x;
    const int w = tid >> 6, l = tid & 63;
    const int quad = l >> 4, lc = l & 15;
    const int m0 = blockIdx.x * 16;

    // A staging: threads 0..63 (wave 0): r = t>>2, kq = t&3
    const int ar = tid >> 2, akq = tid & 3;
    const half_t* Ap = A + (size_t)(m0 + ar) * K + akq * 8;
    // B staging: thread t stages Bt row n=t, 4 k-chunks
    const half_t* Bp = Bt + (size_t)tid * K;

    half8 ra, rb[4];
    auto fetch = [&](int t) {
        if (tid < 64) ra = *(const half8*)(Ap + t * 32);
        const half_t* bp = Bp + t * 32;
#pragma unroll
        for (int u = 0; u < 4; ++u) rb[u] = *(const half8*)(bp + u * 8);
    };
    auto commit = [&](int buf) {
        if (tid < 64) Asf[buf][ar | (akq << 4)] = ra;
#pragma unroll
        for (int u = 0; u < 4; ++u)
            Bsf[buf][tid >> 4][(tid & 15) | (u << 4)] = rb[u];
    };

    floatx4 zero = {0.f, 0.f, 0.f, 0.f};
    floatx4 acc[4] = {zero, zero, zero, zero};
    const int ktiles = K >> 5;

    fetch(0);
    commit(0);
    __syncthreads();
    for (int t = 0; t < ktiles; ++t) {
        const bool more = (t + 1 < ktiles);
        if (more) fetch(t + 1);
        const int buf = t & 1;
        half8 a = Asf[buf][l];
#pragma unroll
        for (int nt = 0; nt < 4; ++nt)
            acc[nt] = mfma16(a, Bsf[buf][w * 4 + nt][l], acc[nt]);
        __syncthreads();
        if (more) {
            commit((t + 1) & 1);
            __syncthreads();
        }
    }

    float bv[4], gg[4], bb[4];
#pragma unroll
    for (int nt = 0; nt < 4; ++nt) {
        const int col = w * 64 + nt * 16 + lc;
        bv[nt] = bias[col];
        gg[nt] = g[col];
        bb[nt] = be[col];
    }
    float vals[4][4];
#pragma unroll
    for (int reg = 0; reg < 4; ++reg) {
        const int rl = quad * 4 + reg;
        const float* rr = res + (size_t)(m0 + rl) * HID_;
        float s = 0.f, sq = 0.f;
#pragma unroll
        for (int nt = 0; nt < 4; ++nt) {
            float vvv = acc[nt][reg] + bv[nt] + rr[w * 64 + nt * 16 + lc];
            vals[reg][nt] = vvv;
            s += vvv;
            sq += vvv * vvv;
        }
        s = qred_sum(s);
        sq = qred_sum(sq);
        if (lc == 0) { rsum[w][rl] = s; rsq[w][rl] = sq; }
    }
    __syncthreads();
#pragma unroll
    for (int reg = 0; reg < 4; ++reg) {
        const int rl = quad * 4 + reg;
        float tot = rsum[0][rl] + rsum[1][rl] + rsum[2][rl] + rsum[3][rl];
        float tsq = rsq[0][rl] + rsq[1][rl] + rsq[2][rl] + rsq[3][rl];
        float mean = tot * (1.f / HID_);
        float var = tsq * (1.f / HID_) - mean * mean;
        float rstd = rsqrtf(var + 1e-12f);
#pragma unroll
        for (int nt = 0; nt < 4; ++nt) {
            float o = (vals[reg][nt] - mean) * rstd * gg[nt] + bb[nt];
            const size_t ci = (size_t)(m0 + rl) * HID_ + w * 64 + nt * 16 + lc;
            out32[ci] = o;
            if (WRITE16) out16[ci] = (half_t)o;
        }
    }
}

// ---------------- ff1: h@W1+b1, GELU ----------------
__global__ __launch_bounds__(256) void ff1_mfma(
    const half_t* __restrict__ h16, const half_t* __restrict__ W1T,
    const float* __restrict__ b1, half_t* __restrict__ f116)
{
    mgemm<EP_GELU>(h16, HID_, W1T, HID_, HID_, blockIdx.y * 64, blockIdx.x * 64,
                   b1, nullptr, f116, FF_, nullptr, nullptr, nullptr, nullptr, 0);
}

// ---------------- launch ----------------
extern "C" void kernel_launch(void* const* d_in, const int* in_sizes, int n_in,
                              void* d_out, int out_size, void* d_ws, size_t ws_size,
                              hipStream_t stream) {
    const float* x        = (const float*)d_in[0];
    const float* mask     = (const float*)d_in[1];
    const float* Wq       = (const float*)d_in[2];
    const float* bq       = (const float*)d_in[3];
    const float* Wk       = (const float*)d_in[4];
    const float* bk       = (const float*)d_in[5];
    const float* Wv       = (const float*)d_in[6];
    const float* bv       = (const float*)d_in[7];
    const float* order_w  = (const float*)d_in[8];
    const float* order_b  = (const float*)d_in[9];
    const float* dist_w   = (const float*)d_in[10];
    const float* dist_b   = (const float*)d_in[11];
    const float* scalar   = (const float*)d_in[12];
    const float* AWq      = (const float*)d_in[13];
    const float* Abq      = (const float*)d_in[14];
    const float* AWk      = (const float*)d_in[15];
    const float* Abk      = (const float*)d_in[16];
    const float* Wd       = (const float*)d_in[17];
    const float* bd       = (const float*)d_in[18];
    const float* g1       = (const float*)d_in[19];
    const float* beta1    = (const float*)d_in[20];
    const float* W1       = (const float*)d_in[21];
    const float* b1       = (const float*)d_in[22];
    const float* W2       = (const float*)d_in[23];
    const float* b2       = (const float*)d_in[24];
    const float* g2       = (const float*)d_in[25];
    const float* beta2    = (const float*)d_in[26];

    float* ws = (float*)d_ws;
    size_t off = 0;
    auto afl = [&](size_t n) { float* p = ws + off; off += n; return p; };
    auto ahf = [&](size_t nh) { half_t* p = (half_t*)(ws + off); off += nh / 2; return p; };

    half_t* x16   = ahf(M_ * HID_);
    half_t* Wq16n = ahf(HID_ * HID_);
    half_t* Wk16n = ahf(HID_ * HID_);
    half_t* WqT   = ahf(HID_ * HID_);
    half_t* WkT   = ahf(HID_ * HID_);
    half_t* WvT   = ahf(HID_ * HID_);
    half_t* WdT   = ahf(HID_ * HID_);
    half_t* AWqT  = ahf(HID_ * HID_);
    half_t* AWkT  = ahf(HID_ * HID_);
    half_t* W1T   = ahf(HID_ * FF_);
    half_t* W2T   = ahf(HID_ * FF_);
    half_t* WcqT  = ahf(HID_ * HID_);
    half_t* WckT  = ahf(HID_ * HID_);
    half_t* q16   = ahf(M_ * HID_);
    half_t* k16   = ahf(M_ * HID_);
    half_t* v16   = ahf(M_ * HID_);
    half_t* aq16  = ahf(M_ * HID_);
    half_t* ak16  = ahf(M_ * HID_);
    half_t* ctx16 = ahf(M_ * HID_);
    half_t* h16   = ahf(M_ * HID_);
    half_t* f116  = ahf(M_ * FF_);
    float* hb32 = afl(M_ * HID_);
    float* bcq  = afl(256);
    float* bck  = afl(256);
    float* qoA  = afl(B_ * H_ * S_);
    float* qdA  = afl(B_ * H_ * S_);
    float* koA  = afl(B_ * H_ * S_);
    float* kdA  = afl(B_ * H_ * S_);

    prep_kernel<<<dim3(16, 16, 11), 256, 0, stream>>>(
        x, Wq, Wk, Wv, Wd, AWq, AWk, W1, W2,
        x16, Wq16n, Wk16n, WqT, WkT, WvT, WdT, AWqT, AWkT, W1T, W2T);
    compose_mfma<<<dim3(4, 5, 2), 256, 0, stream>>>(
        AWqT, AWkT, Wq16n, Wk16n, AWq, AWk, bq, bk, Abq, Abk, WcqT, WckT, bcq, bck);
    xgemm5<<<dim3(4, 16, 5), 256, 0, stream>>>(
        x16, WqT, bq, WkT, bk, WvT, bv, WcqT, bcq, WckT, bck, order_w, dist_w,
        q16, k16, v16, aq16, ak16, qoA, qdA, koA, kdA);
    attn_fused<<<64, 256, 0, stream>>>(
        q16, k16, v16, aq16, ak16, qoA, qdA, koA, kdA,
        mask, order_b, dist_b, scalar, ctx16);
    gemmln<1><<<64, 256, 0, stream>>>(ctx16, WdT, HID_, bd, x, g1, beta1, hb32, h16);
    ff1_mfma<<<dim3(16, 16), 256, 0, stream>>>(h16, W1T, b1, f116);
    gemmln<0><<<64, 256, 0, stream>>>(f116, W2T, FF_, b2, hb32, g2, beta2,
                                      (float*)d_out, nullptr);
}

// Round 7
// 169.436 us; speedup vs baseline: 1.1755x; 1.1552x over previous
//
#include <hip/hip_runtime.h>
#include <hip/hip_bf16.h>
#include <math.h>

// Problem constants
#define B_  8
#define S_  128
#define HID_ 256
#define H_  4
#define DH_ 64
#define FF_ 1024
#define M_  (B_ * S_)   // 1024 rows

typedef _Float16 half_t;
typedef __attribute__((ext_vector_type(8))) _Float16 half8;
typedef __attribute__((ext_vector_type(4))) float floatx4;

enum { EP_F32 = 0, EP_F16 = 1, EP_F16B = 2, EP_GELU = 3, EP_PROJ = 4 };

__device__ __forceinline__ floatx4 mfma16(half8 a, half8 b, floatx4 c) {
    return __builtin_amdgcn_mfma_f32_16x16x32_f16(a, b, c, 0, 0, 0);
}

// ---------------- reductions ----------------
__device__ __forceinline__ float wred_sum(float v) {
#pragma unroll
    for (int o = 32; o >= 1; o >>= 1) v += __shfl_xor(v, o, 64);
    return v;
}
__device__ __forceinline__ float block_sum_256(float v, float* s4, int tid) {
    v = wred_sum(v);
    __syncthreads();
    if ((tid & 63) == 0) s4[tid >> 6] = v;
    __syncthreads();
    return s4[0] + s4[1] + s4[2] + s4[3];
}
// 16-lane group reductions (shfl_xor < 16 stays in group)
__device__ __forceinline__ float qred_sum(float v) {
#pragma unroll
    for (int o = 1; o < 16; o <<= 1) v += __shfl_xor(v, o, 64);
    return v;
}
__device__ __forceinline__ float qred_max(float v) {
#pragma unroll
    for (int o = 1; o < 16; o <<= 1) v = fmaxf(v, __shfl_xor(v, o, 64));
    return v;
}
// softmax over 128 logits: 8 per lane across a 16-lane group (fast exp)
__device__ __forceinline__ void sm8(float (&v)[8]) {
    float m = v[0];
#pragma unroll
    for (int j = 1; j < 8; ++j) m = fmaxf(m, v[j]);
    m = qred_max(m);
    float s = 0.f;
#pragma unroll
    for (int j = 0; j < 8; ++j) { v[j] = __expf(v[j] - m); s += v[j]; }
    s = qred_sum(s);
    float r = 1.f / s;
#pragma unroll
    for (int j = 0; j < 8; ++j) v[j] *= r;
}

// ---------------- fp16 MFMA GEMM core (64x64 tile) ----------------
template<int EPI>
__device__ __forceinline__ void mgemm(
    const half_t* __restrict__ A, int ldA,
    const half_t* __restrict__ Bt, int ldB,
    int kLen, int m0, int n0,
    const float* __restrict__ bias,
    float* __restrict__ Cf, half_t* __restrict__ Ch, int ldC,
    const float* __restrict__ pw1, const float* __restrict__ pw2,
    float* __restrict__ po1, float* __restrict__ po2, int hsel)
{
    __shared__ half8 Asf[2][4][64];
    __shared__ half8 Bsf[2][4][64];

    const int tid = threadIdx.x;
    const int w = tid >> 6, l = tid & 63;
    const int sr = tid >> 2;
    const int sq = tid & 3;
    const int sdst = (sr & 15) | (sq << 4);
    const int smt = sr >> 4;
    const half_t* Ap = A + (size_t)(m0 + sr) * ldA + sq * 8;
    const half_t* Bp = Bt + (size_t)(n0 + sr) * ldB + sq * 8;

    half8 ra, rb;
    auto fetch = [&](int t) {
        ra = *(const half8*)(Ap + t * 32);
        rb = *(const half8*)(Bp + t * 32);
    };
    auto commit = [&](int buf) {
        Asf[buf][smt][sdst] = ra;
        Bsf[buf][smt][sdst] = rb;
    };

    floatx4 zero = {0.f, 0.f, 0.f, 0.f};
    floatx4 acc[4] = {zero, zero, zero, zero};
    const int kt = kLen >> 5;

    fetch(0);
    commit(0);
    __syncthreads();
    for (int t = 0; t < kt; ++t) {
        const bool more = (t + 1 < kt);
        if (more) fetch(t + 1);
        const int buf = t & 1;
        half8 a = Asf[buf][w][l];
        acc[0] = mfma16(a, Bsf[buf][0][l], acc[0]);
        acc[1] = mfma16(a, Bsf[buf][1][l], acc[1]);
        acc[2] = mfma16(a, Bsf[buf][2][l], acc[2]);
        acc[3] = mfma16(a, Bsf[buf][3][l], acc[3]);
        __syncthreads();
        if (more) {
            commit((t + 1) & 1);
            __syncthreads();
        }
    }

    const int quad = l >> 4, lc = l & 15;
    const int rowb = m0 + w * 16 + quad * 4;
    float bvv[4] = {0.f, 0.f, 0.f, 0.f};
    if (EPI >= EP_F16B) {
#pragma unroll
        for (int nt = 0; nt < 4; ++nt) bvv[nt] = bias[n0 + nt * 16 + lc];
    }
    float pw1v[4], pw2v[4];
    if (EPI == EP_PROJ) {
#pragma unroll
        for (int nt = 0; nt < 4; ++nt) {
            pw1v[nt] = pw1[nt * 16 + lc];
            pw2v[nt] = pw2[nt * 16 + lc];
        }
    }
#pragma unroll
    for (int rr = 0; rr < 4; ++rr) {
        float ov[4];
#pragma unroll
        for (int nt = 0; nt < 4; ++nt) {
            float o = acc[nt][rr];
            if (EPI >= EP_F16B) o += bvv[nt];
            if (EPI == EP_GELU) o = 0.5f * o * (1.f + erff(o * 0.70710678118654752f));
            ov[nt] = o;
            const size_t ci = (size_t)(rowb + rr) * ldC + n0 + nt * 16 + lc;
            if (EPI == EP_F32) Cf[ci] = o;
            else Ch[ci] = (half_t)o;
        }
        if (EPI == EP_PROJ) {
            float po = ov[0] * pw1v[0] + ov[1] * pw1v[1] + ov[2] * pw1v[2] + ov[3] * pw1v[3];
            float pd = ov[0] * pw2v[0] + ov[1] * pw2v[1] + ov[2] * pw2v[2] + ov[3] * pw2v[3];
#pragma unroll
            for (int off = 1; off < 16; off <<= 1) {
                po += __shfl_xor(po, off, 64);
                pd += __shfl_xor(pd, off, 64);
            }
            if (lc == 0) {
                const int m = rowb + rr;
                const int idx = ((m >> 7) * H_ + hsel) * S_ + (m & 127);
                po1[idx] = po;
                po2[idx] = pd;
            }
        }
    }
}

// ---------------- prep: fp32 -> fp16 converts + transposes ----------------
__global__ __launch_bounds__(256) void prep_kernel(
    const float* __restrict__ x,
    const float* __restrict__ Wq, const float* __restrict__ Wk,
    const float* __restrict__ Wv, const float* __restrict__ Wd,
    const float* __restrict__ AWq, const float* __restrict__ AWk,
    const float* __restrict__ W1, const float* __restrict__ W2,
    half_t* __restrict__ x16, half_t* __restrict__ Wq16n, half_t* __restrict__ Wk16n,
    half_t* __restrict__ WqT, half_t* __restrict__ WkT, half_t* __restrict__ WvT,
    half_t* __restrict__ WdT, half_t* __restrict__ AWqT, half_t* __restrict__ AWkT,
    half_t* __restrict__ W1T, half_t* __restrict__ W2T)
{
    const int z = blockIdx.z, bx = blockIdx.x, by = blockIdx.y;
    const int tid = threadIdx.x;
    if (z < 3) {
        const float* src = (z == 0) ? x : (z == 1) ? Wq : Wk;
        half_t* dst = (z == 0) ? x16 : (z == 1) ? Wq16n : Wk16n;
        const int total = (z == 0) ? M_ * HID_ : HID_ * HID_;
        const int bid = by * 16 + bx;
        if (bid * 1024 < total) {
            const int base = bid * 1024 + tid * 4;
            float4 vv = *(const float4*)(src + base);
            dst[base + 0] = (half_t)vv.x;
            dst[base + 1] = (half_t)vv.y;
            dst[base + 2] = (half_t)vv.z;
            dst[base + 3] = (half_t)vv.w;
        }
        return;
    }
    const float* src; half_t* dst; int K, N, k0, n0;
    if (z <= 8) {
        const float* ins[6] = {Wq, Wk, Wv, Wd, AWq, AWk};
        half_t* outs[6] = {WqT, WkT, WvT, WdT, AWqT, AWkT};
        src = ins[z - 3]; dst = outs[z - 3];
        K = 256; N = 256; k0 = bx * 64; n0 = by * 64;
        if (bx >= 4 || by >= 4) return;
    } else if (z == 9) {
        src = W1; dst = W1T; K = 256; N = 1024;
        k0 = bx * 64; n0 = by * 64;
        if (bx >= 4) return;
    } else {
        src = W2; dst = W2T; K = 1024; N = 256;
        k0 = by * 64; n0 = bx * 64;
        if (bx >= 4) return;
    }
    __shared__ half_t tl[64][72];
    const int r = tid >> 2, c0 = (tid & 3) * 16;
#pragma unroll 4
    for (int i = 0; i < 16; ++i)
        tl[c0 + i][r] = (half_t)src[(size_t)(k0 + r) * N + n0 + c0 + i];
    __syncthreads();
#pragma unroll 4
    for (int i = 0; i < 16; ++i)
        dst[(size_t)(n0 + r) * K + k0 + c0 + i] = tl[r][c0 + i];
}

// ---------------- compose: WcT = AW^T @ W^T (fp16), bc = b@AW + Ab ----------
__global__ __launch_bounds__(256) void compose_mfma(
    const half_t* __restrict__ AWqT, const half_t* __restrict__ AWkT,
    const half_t* __restrict__ Wq16n, const half_t* __restrict__ Wk16n,
    const float* __restrict__ AWq, const float* __restrict__ AWk,
    const float* __restrict__ bq, const float* __restrict__ bk,
    const float* __restrict__ Abq, const float* __restrict__ Abk,
    half_t* __restrict__ WcqT, half_t* __restrict__ WckT,
    float* __restrict__ bcq, float* __restrict__ bck)
{
    const int z = blockIdx.z;
    if (blockIdx.y < 4) {
        const half_t* A = z ? AWkT : AWqT;
        const half_t* Bt = z ? Wk16n : Wq16n;
        half_t* C = z ? WckT : WcqT;
        mgemm<EP_F16>(A, HID_, Bt, HID_, HID_, blockIdx.y * 64, blockIdx.x * 64,
                      nullptr, nullptr, C, HID_, nullptr, nullptr, nullptr, nullptr, 0);
    } else {
        __shared__ float red[4][64];
        const float* bsrc = z ? bk : bq;
        const float* AW   = z ? AWk : AWq;
        const float* Ab   = z ? Abk : Abq;
        float* bco        = z ? bck : bcq;
        int t = threadIdx.x, l = t & 63, kc = t >> 6;
        int n = blockIdx.x * 64 + l;
        float p = 0.f;
#pragma unroll 8
        for (int kk = 0; kk < 64; ++kk) {
            int k = kc * 64 + kk;
            p = fmaf(bsrc[k], AW[(size_t)k * HID_ + n], p);
        }
        red[kc][l] = p;
        __syncthreads();
        if (kc == 0)
            bco[n] = red[0][l] + red[1][l] + red[2][l] + red[3][l] + Ab[n];
    }
}

// ---------------- 5 projections of x in one launch ----------------
__global__ __launch_bounds__(256) void xgemm5(
    const half_t* __restrict__ x16,
    const half_t* __restrict__ WqT, const float* __restrict__ bq,
    const half_t* __restrict__ WkT, const float* __restrict__ bk,
    const half_t* __restrict__ WvT, const float* __restrict__ bv,
    const half_t* __restrict__ WcqT, const float* __restrict__ bcq,
    const half_t* __restrict__ WckT, const float* __restrict__ bck,
    const float* __restrict__ order_w, const float* __restrict__ dist_w,
    half_t* __restrict__ q16, half_t* __restrict__ k16, half_t* __restrict__ v16,
    half_t* __restrict__ aq16, half_t* __restrict__ ak16,
    float* __restrict__ qoA, float* __restrict__ qdA,
    float* __restrict__ koA, float* __restrict__ kdA)
{
    const int z = blockIdx.z;
    const int m0 = blockIdx.y * 64, n0 = blockIdx.x * 64;
    if (z == 0)
        mgemm<EP_PROJ>(x16, HID_, WqT, HID_, HID_, m0, n0, bq, nullptr, q16, HID_,
                       order_w, dist_w, qoA, qdA, blockIdx.x);
    else if (z == 1)
        mgemm<EP_PROJ>(x16, HID_, WkT, HID_, HID_, m0, n0, bk, nullptr, k16, HID_,
                       order_w + DH_, dist_w + DH_, koA, kdA, blockIdx.x);
    else if (z == 2)
        mgemm<EP_F16B>(x16, HID_, WvT, HID_, HID_, m0, n0, bv, nullptr, v16, HID_,
                       nullptr, nullptr, nullptr, nullptr, 0);
    else if (z == 3)
        mgemm<EP_F16B>(x16, HID_, WcqT, HID_, HID_, m0, n0, bcq, nullptr, aq16, HID_,
                       nullptr, nullptr, nullptr, nullptr, 0);
    else
        mgemm<EP_F16B>(x16, HID_, WckT, HID_, HID_, m0, n0, bck, nullptr, ak16, HID_,
                       nullptr, nullptr, nullptr, nullptr, 0);
}

// ---------------- fused attention: one wave per 16-row strip --------------
// grid = 256 blocks (bh*8 + rt), 64 threads. Full-machine coverage for the
// VALU-heavy softmax chain (the r5/r6 regression was 64-block coverage).
__global__ __launch_bounds__(64) void attn_fused(
    const half_t* __restrict__ q16, const half_t* __restrict__ k16,
    const half_t* __restrict__ v16, const half_t* __restrict__ aq16,
    const half_t* __restrict__ ak16,
    const float* __restrict__ qoA, const float* __restrict__ qdA,
    const float* __restrict__ koA, const float* __restrict__ kdA,
    const float* __restrict__ mask,
    const float* __restrict__ order_b_p, const float* __restrict__ dist_b_p,
    const float* __restrict__ scalar_p,
    half_t* __restrict__ ctx16)
{
    __shared__ half8 Qf[2][64], AQf[2][64];     // 2 KB + 2 KB
    __shared__ half8 Kf[2][8][64], AKf[2][8][64]; // 16 KB + 16 KB
    __shared__ half_t Vt[64][136];              // 17 KB, V^T [d][j]
    __shared__ half_t Pm[16][136];              // 4.25 KB

    const int l = threadIdx.x;
    const int quad = l >> 4, lc = l & 15;
    const int bh = blockIdx.x >> 3, rt = blockIdx.x & 7;
    const int b = bh >> 2, h = bh & 3;
    const size_t hoff = (size_t)b * S_ * HID_ + h * DH_;

    // ---- stage Q/AQ (16 rows), K/AK (128 rows) as MFMA fragments ----
#pragma unroll
    for (int u = 0; u < 2; ++u) {
        int idx = u * 64 + l;
        int r = idx >> 3, c = idx & 7;
        size_t g = hoff + (size_t)(rt * 16 + r) * HID_ + c * 8;
        int kt = c >> 2, sl = r | ((c & 3) << 4);
        Qf[kt][sl]  = *(const half8*)(q16 + g);
        AQf[kt][sl] = *(const half8*)(aq16 + g);
    }
#pragma unroll
    for (int u = 0; u < 16; ++u) {
        int idx = u * 64 + l;
        int j = idx >> 3, c = idx & 7;
        size_t g = hoff + (size_t)j * HID_ + c * 8;
        int kt = c >> 2, jt = j >> 4, sl = (j & 15) | ((c & 3) << 4);
        Kf[kt][jt][sl]  = *(const half8*)(k16 + g);
        AKf[kt][jt][sl] = *(const half8*)(ak16 + g);
    }
    // V transposed; lanes span j for fixed (c,e) -> conflict-free LDS writes
#pragma unroll
    for (int u = 0; u < 16; ++u) {
        int j = (u >> 3) * 64 + l;
        int c = u & 7;
        half8 vv = *(const half8*)(v16 + hoff + (size_t)j * HID_ + c * 8);
#pragma unroll
        for (int e = 0; e < 8; ++e) Vt[c * 8 + e][j] = vv[e];
    }
    __syncthreads();

    // ---- S = Q.K^T, AS = AQ.AK^T (16 rows x 128 j) ----
    floatx4 zero = {0.f, 0.f, 0.f, 0.f};
    floatx4 accS[8], accA[8];
#pragma unroll
    for (int jt = 0; jt < 8; ++jt) { accS[jt] = zero; accA[jt] = zero; }
#pragma unroll
    for (int kt = 0; kt < 2; ++kt) {
        half8 a0 = Qf[kt][l];
        half8 a1 = AQf[kt][l];
#pragma unroll
        for (int jt = 0; jt < 8; ++jt) {
            accS[jt] = mfma16(a0, Kf[kt][jt][l], accS[jt]);
            accA[jt] = mfma16(a1, AKf[kt][jt][l], accA[jt]);
        }
    }

    // ---- 5-softmax chain in registers (16-lane group = one row) ----
    const float ob = order_b_p[0], db = dist_b_p[0];
    const float scl = scalar_p[0];
    const float s2 = scl * scl;
    const float inv = 0.125f;
    float kov[8], kdv[8];
#pragma unroll
    for (int jt = 0; jt < 8; ++jt) {
        kov[jt] = koA[bh * S_ + jt * 16 + lc];
        kdv[jt] = kdA[bh * S_ + jt * 16 + lc];
    }
#pragma unroll
    for (int reg = 0; reg < 4; ++reg) {
        const int il = quad * 4 + reg;          // local row 0..15
        const int i  = rt * 16 + il;            // global query index
        float qo = qoA[bh * S_ + i], qd = qdA[bh * S_ + i];
        const float* mrow = mask + ((size_t)(b * S_ + i)) * S_;
        float mk[8], lg[8], as_[8];
#pragma unroll
        for (int jt = 0; jt < 8; ++jt) {
            mk[jt] = mrow[jt * 16 + lc];
            lg[jt] = accS[jt][reg];
            as_[jt] = accA[jt][reg];
        }
        float p0[8];
#pragma unroll
        for (int jt = 0; jt < 8; ++jt) p0[jt] = lg[jt] * inv + mk[jt];
        sm8(p0);                                    // origin_probs
        float p1[8];
#pragma unroll
        for (int jt = 0; jt < 8; ++jt) {
            int j = jt * 16 + lc;
            float pr = 1.f / (1.f + __expf(-(qo + kov[jt] + ob)));
            float sel = (j > i) ? pr : 1.f - pr;
            float erro = __logf(sel + 1e-24f);
            float gd = __logf(fabsf((float)(j - i)) + 1.f);
            float dd = gd - (qd + kdv[jt] + db);
            p1[jt] = (lg[jt] + erro - 0.5f * dd * dd * s2) * inv + mk[jt];
        }
        sm8(p1);                                    // rich_probs
#pragma unroll
        for (int jt = 0; jt < 8; ++jt) p0[jt] += 0.5f * p1[jt];
        sm8(p0);                                    // combined
#pragma unroll
        for (int jt = 0; jt < 8; ++jt) p1[jt] = as_[jt] * inv + mk[jt];
        sm8(p1);                                    // attack_probs
#pragma unroll
        for (int jt = 0; jt < 8; ++jt) p0[jt] += 0.5f * p1[jt];
        sm8(p0);                                    // final_probs
#pragma unroll
        for (int jt = 0; jt < 8; ++jt) Pm[il][jt * 16 + lc] = (half_t)p0[jt];
    }
    __syncthreads();

    // ---- PV: ctx strip = P @ V via MFMA (b128 LDS reads) ----
    half8 pa_[4];
#pragma unroll
    for (int kt = 0; kt < 4; ++kt)
        pa_[kt] = *(const half8*)&Pm[lc][kt * 32 + quad * 8];
    floatx4 apv[4];
#pragma unroll
    for (int nt = 0; nt < 4; ++nt) apv[nt] = zero;
#pragma unroll
    for (int nt = 0; nt < 4; ++nt) {
#pragma unroll
        for (int kt = 0; kt < 4; ++kt) {
            half8 vf = *(const half8*)&Vt[nt * 16 + lc][kt * 32 + quad * 8];
            apv[nt] = mfma16(pa_[kt], vf, apv[nt]);
        }
    }
#pragma unroll
    for (int nt = 0; nt < 4; ++nt) {
#pragma unroll
        for (int reg = 0; reg < 4; ++reg) {
            int i = rt * 16 + quad * 4 + reg;
            ctx16[hoff + (size_t)i * HID_ + nt * 16 + lc] = (half_t)apv[nt][reg];
        }
    }
}

// ---------------- dense: ctx@Wd (fp32 out) ----------------
__global__ __launch_bounds__(256) void dense_mfma(
    const half_t* __restrict__ ctx16, const half_t* __restrict__ WdT,
    float* __restrict__ dn)
{
    mgemm<EP_F32>(ctx16, HID_, WdT, HID_, HID_, blockIdx.y * 64, blockIdx.x * 64,
                  nullptr, dn, nullptr, HID_, nullptr, nullptr, nullptr, nullptr, 0);
}

// ---------------- ff1: h@W1+b1, GELU ----------------
__global__ __launch_bounds__(256) void ff1_mfma(
    const half_t* __restrict__ h16, const half_t* __restrict__ W1T,
    const float* __restrict__ b1, half_t* __restrict__ f116)
{
    mgemm<EP_GELU>(h16, HID_, W1T, HID_, HID_, blockIdx.y * 64, blockIdx.x * 64,
                   b1, nullptr, f116, FF_, nullptr, nullptr, nullptr, nullptr, 0);
}

// ---------------- ff2: split-K 2 x 512 ----------------
__global__ __launch_bounds__(256) void ff2_mfma(
    const half_t* __restrict__ f116, const half_t* __restrict__ W2T,
    float* __restrict__ p0, float* __restrict__ p1)
{
    const int z = blockIdx.z;
    float* C = z ? p1 : p0;
    mgemm<EP_F32>(f116 + z * 512, FF_, W2T + z * 512, FF_, 512,
                  blockIdx.y * 64, blockIdx.x * 64,
                  nullptr, C, nullptr, HID_, nullptr, nullptr, nullptr, nullptr, 0);
}

// ---------------- LN kernels ----------------
__global__ __launch_bounds__(256) void ln1_kernel(
    const float* __restrict__ dn, const float* __restrict__ bd,
    const float* __restrict__ x,
    const float* __restrict__ g1, const float* __restrict__ beta1,
    float* __restrict__ h32, half_t* __restrict__ h16)
{
    __shared__ float s4[4];
    const int row = blockIdx.x;
    const int n = threadIdx.x;
    const size_t idx = (size_t)row * HID_ + n;
    float val = dn[idx] + bd[n] + x[idx];
    float mean = block_sum_256(val, s4, n) * (1.f / HID_);
    float dv = val - mean;
    float var = block_sum_256(dv * dv, s4, n) * (1.f / HID_);
    float r = dv * rsqrtf(var + 1e-12f) * g1[n] + beta1[n];
    h32[idx] = r;
    h16[idx] = (half_t)r;
}

__global__ __launch_bounds__(256) void ln2_kernel(
    const float* __restrict__ p0, const float* __restrict__ p1,
    const float* __restrict__ b2, const float* __restrict__ h32,
    const float* __restrict__ g2, const float* __restrict__ beta2,
    float* __restrict__ out)
{
    __shared__ float s4[4];
    const int row = blockIdx.x;
    const int n = threadIdx.x;
    const size_t idx = (size_t)row * HID_ + n;
    float val = p0[idx] + p1[idx] + b2[n] + h32[idx];
    float mean = block_sum_256(val, s4, n) * (1.f / HID_);
    float dv = val - mean;
    float var = block_sum_256(dv * dv, s4, n) * (1.f / HID_);
    out[idx] = dv * rsqrtf(var + 1e-12f) * g2[n] + beta2[n];
}

// ---------------- launch ----------------
extern "C" void kernel_launch(void* const* d_in, const int* in_sizes, int n_in,
                              void* d_out, int out_size, void* d_ws, size_t ws_size,
                              hipStream_t stream) {
    const float* x        = (const float*)d_in[0];
    const float* mask     = (const float*)d_in[1];
    const float* Wq       = (const float*)d_in[2];
    const float* bq       = (const float*)d_in[3];
    const float* Wk       = (const float*)d_in[4];
    const float* bk       = (const float*)d_in[5];
    const float* Wv       = (const float*)d_in[6];
    const float* bv       = (const float*)d_in[7];
    const float* order_w  = (const float*)d_in[8];
    const float* order_b  = (const float*)d_in[9];
    const float* dist_w   = (const float*)d_in[10];
    const float* dist_b   = (const float*)d_in[11];
    const float* scalar   = (const float*)d_in[12];
    const float* AWq      = (const float*)d_in[13];
    const float* Abq      = (const float*)d_in[14];
    const float* AWk      = (const float*)d_in[15];
    const float* Abk      = (const float*)d_in[16];
    const float* Wd       = (const float*)d_in[17];
    const float* bd       = (const float*)d_in[18];
    const float* g1       = (const float*)d_in[19];
    const float* beta1    = (const float*)d_in[20];
    const float* W1       = (const float*)d_in[21];
    const float* b1       = (const float*)d_in[22];
    const float* W2       = (const float*)d_in[23];
    const float* b2       = (const float*)d_in[24];
    const float* g2       = (const float*)d_in[25];
    const float* beta2    = (const float*)d_in[26];

    float* ws = (float*)d_ws;
    size_t off = 0;
    auto afl = [&](size_t n) { float* p = ws + off; off += n; return p; };
    auto ahf = [&](size_t nh) { half_t* p = (half_t*)(ws + off); off += nh / 2; return p; };

    half_t* x16   = ahf(M_ * HID_);
    half_t* Wq16n = ahf(HID_ * HID_);
    half_t* Wk16n = ahf(HID_ * HID_);
    half_t* WqT   = ahf(HID_ * HID_);
    half_t* WkT   = ahf(HID_ * HID_);
    half_t* WvT   = ahf(HID_ * HID_);
    half_t* WdT   = ahf(HID_ * HID_);
    half_t* AWqT  = ahf(HID_ * HID_);
    half_t* AWkT  = ahf(HID_ * HID_);
    half_t* W1T   = ahf(HID_ * FF_);
    half_t* W2T   = ahf(HID_ * FF_);
    half_t* WcqT  = ahf(HID_ * HID_);
    half_t* WckT  = ahf(HID_ * HID_);
    half_t* q16   = ahf(M_ * HID_);
    half_t* k16   = ahf(M_ * HID_);
    half_t* v16   = ahf(M_ * HID_);
    half_t* aq16  = ahf(M_ * HID_);
    half_t* ak16  = ahf(M_ * HID_);
    half_t* ctx16 = ahf(M_ * HID_);
    half_t* h16   = ahf(M_ * HID_);
    half_t* f116  = ahf(M_ * FF_);
    float* dnb  = afl(M_ * HID_);
    float* hb32 = afl(M_ * HID_);
    float* pf0  = afl(M_ * HID_);
    float* pf1  = afl(M_ * HID_);
    float* bcq  = afl(256);
    float* bck  = afl(256);
    float* qoA  = afl(B_ * H_ * S_);
    float* qdA  = afl(B_ * H_ * S_);
    float* koA  = afl(B_ * H_ * S_);
    float* kdA  = afl(B_ * H_ * S_);

    prep_kernel<<<dim3(16, 16, 11), 256, 0, stream>>>(
        x, Wq, Wk, Wv, Wd, AWq, AWk, W1, W2,
        x16, Wq16n, Wk16n, WqT, WkT, WvT, WdT, AWqT, AWkT, W1T, W2T);
    compose_mfma<<<dim3(4, 5, 2), 256, 0, stream>>>(
        AWqT, AWkT, Wq16n, Wk16n, AWq, AWk, bq, bk, Abq, Abk, WcqT, WckT, bcq, bck);
    xgemm5<<<dim3(4, 16, 5), 256, 0, stream>>>(
        x16, WqT, bq, WkT, bk, WvT, bv, WcqT, bcq, WckT, bck, order_w, dist_w,
        q16, k16, v16, aq16, ak16, qoA, qdA, koA, kdA);
    attn_fused<<<256, 64, 0, stream>>>(
        q16, k16, v16, aq16, ak16, qoA, qdA, koA, kdA,
        mask, order_b, dist_b, scalar, ctx16);
    dense_mfma<<<dim3(4, 16), 256, 0, stream>>>(ctx16, WdT, dnb);
    ln1_kernel<<<M_, 256, 0, stream>>>(dnb, bd, x, g1, beta1, hb32, h16);
    ff1_mfma<<<dim3(16, 16), 256, 0, stream>>>(h16, W1T, b1, f116);
    ff2_mfma<<<dim3(4, 16, 2), 256, 0, stream>>>(f116, W2T, pf0, pf1);
    ln2_kernel<<<M_, 256, 0, stream>>>(pf0, pf1, b2, hb32, g2, beta2, (float*)d_out);
}